// Round 5
// baseline (815.737 us; speedup 1.0000x reference)
//
#include <hip/hip_runtime.h>
#include <math.h>

#define EPSF 1e-7f
#define KPAD 1024
#define M_PAD 50176   // 196 * 256
#define NWG2 784      // 196 * 4, = 8 * 98

typedef __attribute__((ext_vector_type(8))) short bf16x8;
typedef __attribute__((ext_vector_type(4))) float f32x4;
typedef __attribute__((ext_vector_type(4))) unsigned short us4;
typedef __attribute__((ext_vector_type(8))) unsigned short us8;

__device__ inline unsigned short f2bf(float f) {
  unsigned u = __float_as_uint(f);
  return (unsigned short)((u + 0x7FFFu + ((u >> 16) & 1u)) >> 16);
}
__device__ inline float bf2f(unsigned short s) {
  return __uint_as_float(((unsigned)s) << 16);
}

__device__ inline float block_sum256(float v, float* s4) {
#pragma unroll
  for (int o = 32; o > 0; o >>= 1) v += __shfl_down(v, o);
  int lane = threadIdx.x & 63, w = threadIdx.x >> 6;
  __syncthreads();
  if (lane == 0) s4[w] = v;
  __syncthreads();
  return s4[0] + s4[1] + s4[2] + s4[3];
}

__device__ inline void gload_lds16(const void* g, void* l) {
  __builtin_amdgcn_global_load_lds((const __attribute__((address_space(1))) void*)g,
                                   (__attribute__((address_space(3))) void*)l, 16, 0, 0);
}

// ---------- conversions ----------
__global__ __launch_bounds__(256) void cvt_rows_bf16(const float* __restrict__ x,
                                                     unsigned short* __restrict__ o) {
  int i = blockIdx.x, t = threadIdx.x;
  float4 v = *(const float4*)(x + (size_t)i * 1024 + 4 * t);
  us4 u = {f2bf(v.x), f2bf(v.y), f2bf(v.z), f2bf(v.w)};
  *(us4*)(o + (size_t)i * 1024 + 4 * t) = u;
}

__global__ __launch_bounds__(256) void cvt_w_bf16(const float* __restrict__ W,
                                                  unsigned short* __restrict__ o,
                                                  int rows, int cols) {
  int r = blockIdx.x, t = threadIdx.x;
  int c0 = 4 * t;
  us4 u;
#pragma unroll
  for (int j = 0; j < 4; ++j) {
    int c = c0 + j;
    float v = (r < rows && c < cols) ? W[(size_t)r * cols + c] : 0.0f;
    u[j] = f2bf(v);
  }
  *(us4*)(o + (size_t)r * 1024 + c0) = u;
}

// ---------- GEMM 256x256, BK=32, quad-buffered LDS, counted vmcnt, 1 barrier/K-tile ----
// C[i][j] = bf16(sum_k A16[i][k] * B16[j][k] + bias[j])
__global__ __launch_bounds__(512, 2) void gemm_bt256(const unsigned short* __restrict__ A,
                                                     const unsigned short* __restrict__ B,
                                                     const float* __restrict__ bias,
                                                     unsigned short* __restrict__ C) {
  __shared__ unsigned short lA[4][256 * 32];
  __shared__ unsigned short lB[4][256 * 32];
  const int wg = blockIdx.x;
  const int swz = (wg & 7) * 98 + (wg >> 3);  // bijective: 784 = 8*98
  const int bm = swz >> 2, bn = swz & 3;
  const int tid = threadIdx.x;
  const int wave = tid >> 6, lane = tid & 63;
  const int wr = wave >> 2, wc = wave & 3;   // 2 x 4 wave grid, 128x64 per wave
  const int fr = lane & 15, fg = lane >> 4;
  const int srow = tid >> 2;  // 0..127 staging row within half
  const int sg = tid & 3;     // staging granule

  const unsigned short* Abase = A + (size_t)bm * 256 * KPAD;
  const unsigned short* Bbase = B + (size_t)bn * 256 * KPAD;

  f32x4 acc[8][4];
#pragma unroll
  for (int m = 0; m < 8; ++m)
#pragma unroll
    for (int n2 = 0; n2 < 4; ++n2) acc[m][n2] = (f32x4)0.0f;

  // stage K-tile t (4 gload_lds per wave: A-half0, B-half0, A-half1, B-half1)
  auto STAGE = [&](int t) {
    const int k0 = t * 32;
    const int buf = t & 3;
#pragma unroll
    for (int q = 0; q < 2; ++q) {
      int row = q * 128 + srow;
      int ksrc = k0 + ((sg ^ ((row >> 1) & 3)) << 3);
      gload_lds16(Abase + (size_t)row * KPAD + ksrc, &lA[buf][row * 32 + (sg << 3)]);
      gload_lds16(Bbase + (size_t)row * KPAD + ksrc, &lB[buf][row * 32 + (sg << 3)]);
    }
  };

  auto COMPUTE = [&](int t) {
    const int buf = t & 3;
    bf16x8 a[8], b[4];
#pragma unroll
    for (int m = 0; m < 8; ++m) {
      int row = wr * 128 + m * 16 + fr;
      a[m] = *(const bf16x8*)&lA[buf][row * 32 + ((fg ^ ((row >> 1) & 3)) << 3)];
    }
#pragma unroll
    for (int n2 = 0; n2 < 4; ++n2) {
      int row = wc * 64 + n2 * 16 + fr;
      b[n2] = *(const bf16x8*)&lB[buf][row * 32 + ((fg ^ ((row >> 1) & 3)) << 3)];
    }
    __builtin_amdgcn_s_setprio(1);
#pragma unroll
    for (int m = 0; m < 8; ++m)
#pragma unroll
      for (int n2 = 0; n2 < 4; ++n2)
        acc[m][n2] = __builtin_amdgcn_mfma_f32_16x16x32_bf16(a[m], b[n2], acc[m][n2], 0, 0, 0);
    __builtin_amdgcn_s_setprio(0);
  };

  // prologue: 3 K-tiles in flight
  STAGE(0);
  STAGE(1);
  STAGE(2);
  // main loop: drain my 4 oldest loads (tile t), barrier => tile t fully in LDS,
  // then issue tile t+3 into buf[(t+3)&3] (= buf[(t-1)&3], reads finished last iter).
  for (int t = 0; t < 29; ++t) {
    asm volatile("s_waitcnt vmcnt(8)" ::: "memory");
    __builtin_amdgcn_s_barrier();
    STAGE(t + 3);
    COMPUTE(t);
  }
  asm volatile("s_waitcnt vmcnt(8)" ::: "memory");
  __builtin_amdgcn_s_barrier();
  COMPUTE(29);
  asm volatile("s_waitcnt vmcnt(4)" ::: "memory");
  __builtin_amdgcn_s_barrier();
  COMPUTE(30);
  asm volatile("s_waitcnt vmcnt(0)" ::: "memory");
  __builtin_amdgcn_s_barrier();
  COMPUTE(31);

  // epilogue
  const int crow0 = bm * 256 + wr * 128;
  const int ccol0 = bn * 256 + wc * 64;
#pragma unroll
  for (int m = 0; m < 8; ++m) {
#pragma unroll
    for (int n2 = 0; n2 < 4; ++n2) {
      int col = ccol0 + n2 * 16 + fr;
      float bv = (col < 1023) ? bias[col] : 0.0f;
      int row0 = crow0 + m * 16 + fg * 4;
      unsigned short* cp = C + (size_t)row0 * 1024 + col;
#pragma unroll
      for (int j = 0; j < 4; ++j) cp[(size_t)j * 1024] = f2bf(acc[m][n2][j] + bv);
    }
  }
}

// ---------- per-row expmap scale: sc table + patch raw[1023] = h0/sc ----------
__global__ __launch_bounds__(256) void row_scale(unsigned short* __restrict__ raw,
                                                 float* __restrict__ sc_tab, float sqrtK) {
  __shared__ float s4[4];
  int i = blockIdx.x, t = threadIdx.x;
  const us4 v = *(const us4*)(raw + (size_t)i * 1024 + 4 * t);
  float f0 = bf2f(v[0]), f1 = bf2f(v[1]), f2 = bf2f(v[2]), f3 = bf2f(v[3]);
  if (t == 255) f3 = 0.0f;  // col 1023 pad
  float ss = block_sum256(f0 * f0 + f1 * f1 + f2 * f2 + f3 * f3, s4);
  float un = fmaxf(sqrtf(ss), EPSF);
  float tt = un / sqrtK;
  float e = expf(tt);
  float ch = 0.5f * (e + 1.0f / e), sh = 0.5f * (e - 1.0f / e);
  float h0 = sqrtK * ch, sc = sqrtK * sh / un;
  if (t == 0) sc_tab[i] = sc;
  if (t == 255) raw[(size_t)i * 1024 + 1023] = f2bf(h0 / sc);
}

// ---------- CSR build ----------
__global__ __launch_bounds__(256) void deg_count(const int* __restrict__ ed, int* __restrict__ cnt,
                                                 int nE) {
  int i = blockIdx.x * 256 + threadIdx.x;
  if (i < nE) atomicAdd(&cnt[ed[i]], 1);
}

__global__ __launch_bounds__(256) void scan1(const int* __restrict__ cnt, int* __restrict__ excl,
                                             int* __restrict__ bsum, int n) {
  __shared__ int s[256];
  int t = threadIdx.x;
  int i = blockIdx.x * 256 + t;
  int v = (i < n) ? cnt[i] : 0;
  s[t] = v;
  __syncthreads();
#pragma unroll
  for (int o = 1; o < 256; o <<= 1) {
    int add = (t >= o) ? s[t - o] : 0;
    __syncthreads();
    s[t] += add;
    __syncthreads();
  }
  if (i < n) excl[i] = s[t] - v;
  if (t == 255) bsum[blockIdx.x] = s[t];
}

__global__ __launch_bounds__(256) void scan2(int* __restrict__ bsum, int* __restrict__ boff,
                                             int nb) {
  __shared__ int s[256];
  int t = threadIdx.x;
  int v = (t < nb) ? bsum[t] : 0;
  s[t] = v;
  __syncthreads();
#pragma unroll
  for (int o = 1; o < 256; o <<= 1) {
    int add = (t >= o) ? s[t - o] : 0;
    __syncthreads();
    s[t] += add;
    __syncthreads();
  }
  if (t < nb) boff[t] = s[t] - v;
}

__global__ __launch_bounds__(256) void scan3(int* __restrict__ excl, const int* __restrict__ boff,
                                             int* __restrict__ rowstart, int* __restrict__ fill,
                                             int n, int nE) {
  int i = blockIdx.x * 256 + threadIdx.x;
  if (i < n) {
    int v = excl[i] + boff[blockIdx.x];
    rowstart[i] = v;
    fill[i] = v;
  }
  if (i == 0) rowstart[n] = nE;
}

__global__ __launch_bounds__(256) void bucket_fill(const int* __restrict__ es,
                                                   const int* __restrict__ ed,
                                                   const float* __restrict__ ew,
                                                   int* __restrict__ fill,
                                                   int2* __restrict__ sedge, int nE) {
  int i = blockIdx.x * 256 + threadIdx.x;
  if (i < nE) {
    int d = ed[i];
    int pos = atomicAdd(&fill[d], 1);
    sedge[pos] = make_int2(es[i], __float_as_int(ew[i]));
  }
}

// ---------- gather core: fully-predicated 4-deep batches (no serial remainder) ----------
__device__ inline void gather_row(const unsigned short* __restrict__ h,
                                  const float* __restrict__ sc,
                                  const int2* __restrict__ sedge, int j0, int j1, int t,
                                  float* acc) {
  for (int j = j0; j < j1; j += 4) {
    int2 e[4];
    float w[4];
#pragma unroll
    for (int kk = 0; kk < 4; ++kk) {
      int jj = j + kk;
      int jc = (jj < j1) ? jj : (j1 - 1);
      e[kk] = sedge[jc];
      w[kk] = (jj < j1) ? __int_as_float(e[kk].y) * sc[e[kk].x] : 0.0f;
    }
    us8 v0 = *(const us8*)(h + (size_t)e[0].x * 1024 + 8 * t);
    us8 v1 = *(const us8*)(h + (size_t)e[1].x * 1024 + 8 * t);
    us8 v2 = *(const us8*)(h + (size_t)e[2].x * 1024 + 8 * t);
    us8 v3 = *(const us8*)(h + (size_t)e[3].x * 1024 + 8 * t);
#pragma unroll
    for (int q = 0; q < 8; ++q) {
      acc[q] += w[0] * bf2f(v0[q]);
      acc[q] += w[1] * bf2f(v1[q]);
      acc[q] += w[2] * bf2f(v2[q]);
      acc[q] += w[3] * bf2f(v3[q]);
    }
  }
}

// ---------- gather + centroid + logmap0 + relu -> bf16 tangent (layer-1 tail) ----------
__global__ __launch_bounds__(256) void gather_centroid_tangent(
    const unsigned short* __restrict__ h, const float* __restrict__ sc,
    const int* __restrict__ rs, const int2* __restrict__ sedge,
    unsigned short* __restrict__ u16, float sqrtK, int n) {
  __shared__ float s4[4];
  __shared__ float sm0[2];
  int g = threadIdx.x >> 7;   // sub-block 0/1
  int t = threadIdx.x & 127;  // 0..127
  int i = blockIdx.x * 2 + g;
  bool alive = (i < n);
  int j0 = alive ? rs[i] : 0, j1 = alive ? rs[i + 1] : 0;
  float acc[8] = {0.f, 0.f, 0.f, 0.f, 0.f, 0.f, 0.f, 0.f};
  gather_row(h, sc, sedge, j0, j1, t, acc);
  if (t == 127) sm0[g] = acc[7];  // time coord (col 1023)
  __syncthreads();
  float m0 = sm0[g];
  if (t == 127) acc[7] = 0.0f;
  float ssl = 0.f;
#pragma unroll
  for (int q = 0; q < 8; ++q) ssl += acc[q] * acc[q];
#pragma unroll
  for (int o = 32; o > 0; o >>= 1) ssl += __shfl_down(ssl, o);
  int lane = threadIdx.x & 63, wv = threadIdx.x >> 6;
  if (lane == 0) s4[wv] = ssl;
  __syncthreads();
  float ss = s4[2 * g] + s4[2 * g + 1];

  float l = ss - m0 * m0;
  float denom = sqrtf(fmaxf(fabsf(l), EPSF));
  float c = sqrtK / denom;
  float xn = fmaxf(c * sqrtf(ss), EPSF);
  float theta = fmaxf(m0 / denom, 1.0f + EPSF);
  float d = sqrtK * acoshf(theta);
  float f = c * (d / xn);
  us8 u;
#pragma unroll
  for (int q = 0; q < 8; ++q) u[q] = f2bf(fmaxf(acc[q], 0.0f) * f);
  if (t == 127) u[7] = 0;  // col 1023 pad
  if (alive) *(us8*)(u16 + (size_t)i * 1024 + 8 * t) = u;
}

// ---------- gather + centroid + logmap + relu + expmap + proj -> y (layer-2 tail) ----------
__global__ __launch_bounds__(256) void gather_centroid_final(
    const unsigned short* __restrict__ h, const float* __restrict__ sc,
    const int* __restrict__ rs, const int2* __restrict__ sedge, float* __restrict__ y,
    float sqrtKin, float sqrtKout, int n) {
  __shared__ float s4[4];
  __shared__ float s4b[4];
  __shared__ float sm0[2];
  int g = threadIdx.x >> 7;
  int t = threadIdx.x & 127;
  int i = blockIdx.x * 2 + g;
  bool alive = (i < n);
  int j0 = alive ? rs[i] : 0, j1 = alive ? rs[i + 1] : 0;
  float acc[8] = {0.f, 0.f, 0.f, 0.f, 0.f, 0.f, 0.f, 0.f};
  gather_row(h, sc, sedge, j0, j1, t, acc);
  if (t == 127) sm0[g] = acc[7];
  __syncthreads();
  float m0 = sm0[g];
  if (t == 127) acc[7] = 0.0f;
  float ssl = 0.f;
#pragma unroll
  for (int q = 0; q < 8; ++q) ssl += acc[q] * acc[q];
#pragma unroll
  for (int o = 32; o > 0; o >>= 1) ssl += __shfl_down(ssl, o);
  int lane = threadIdx.x & 63, wv = threadIdx.x >> 6;
  if (lane == 0) s4[wv] = ssl;
  __syncthreads();
  float ss = s4[2 * g] + s4[2 * g + 1];

  float l = ss - m0 * m0;
  float denom = sqrtf(fmaxf(fabsf(l), EPSF));
  float c = sqrtKin / denom;
  float xn = fmaxf(c * sqrtf(ss), EPSF);
  float theta = fmaxf(m0 / denom, 1.0f + EPSF);
  float d = sqrtKin * acoshf(theta);
  float f = c * (d / xn);
  float o_[8];
#pragma unroll
  for (int q = 0; q < 8; ++q) o_[q] = fmaxf(acc[q], 0.0f) * f;
  if (t == 127) o_[7] = 0.0f;
  float ss2l = 0.f;
#pragma unroll
  for (int q = 0; q < 8; ++q) ss2l += o_[q] * o_[q];
#pragma unroll
  for (int o = 32; o > 0; o >>= 1) ss2l += __shfl_down(ss2l, o);
  if (lane == 0) s4b[wv] = ss2l;
  __syncthreads();
  float ss2 = s4b[2 * g] + s4b[2 * g + 1];

  float un = fmaxf(sqrtf(ss2), EPSF);
  float tt = un / sqrtKout;
  float e = expf(tt);
  float ch = 0.5f * (e + 1.0f / e), sh = 0.5f * (e - 1.0f / e);
  float y0 = sqrtKout * ch, scale = sqrtKout * sh / un;
  if (alive) {
    float* yr = y + (size_t)i * 1024;
    int c0 = 8 * t;
#pragma unroll
    for (int q = 0; q < 8; ++q) {
      int col = c0 + q;
      if (col < 1023) yr[1 + col] = scale * o_[q];
    }
    if (t == 0) yr[0] = y0;
  }
}

extern "C" void kernel_launch(void* const* d_in, const int* in_sizes, int n_in,
                              void* d_out, int out_size, void* d_ws, size_t ws_size,
                              hipStream_t stream) {
  const float* x = (const float*)d_in[0];
  const int* es = (const int*)d_in[1];
  const int* ed = (const int*)d_in[2];
  const float* ew = (const float*)d_in[3];
  const float* W1 = (const float*)d_in[4];
  const float* b1 = (const float*)d_in[5];
  const float* W2 = (const float*)d_in[6];
  const float* b2 = (const float*)d_in[7];
  float* y = (float*)d_out;

  const int n = in_sizes[0] / 1024;  // 50000
  const int nE = in_sizes[1];        // 400000
  const int NB = (n + 255) / 256;    // 196
  const int EB = (nE + 255) / 256;

  // workspace layout (offsets 256B-aligned)
  char* ws = (char*)d_ws;
  size_t off = 0;
  auto alloc = [&](size_t bytes) {
    void* p = ws + off;
    off += (bytes + 255) & ~(size_t)255;
    return p;
  };
  unsigned short* u16 = (unsigned short*)alloc((size_t)M_PAD * 1024 * 2);
  unsigned short* w16 = (unsigned short*)alloc((size_t)1024 * 1024 * 2);
  unsigned short* raw16 = (unsigned short*)alloc((size_t)M_PAD * 1024 * 2);
  float* sc_tab = (float*)alloc((size_t)M_PAD * 4);
  int* cnt = (int*)alloc((size_t)(n + 1) * 4);
  int* excl = (int*)alloc((size_t)n * 4);
  int* rowstart = (int*)alloc((size_t)(n + 1) * 4);
  int* fill = (int*)alloc((size_t)n * 4);
  int* bsum = (int*)alloc(256 * 4);
  int* boff = (int*)alloc(256 * 4);
  int2* sedge = (int2*)alloc((size_t)nE * 8);

  const float sK1 = 1.0f;                 // sqrt(K_IN)
  const float sK2 = 1.0488088481701516f;  // sqrt(1.1)
  const float sK3 = 1.0954451150103321f;  // sqrt(1.2)

  const int GB = (n + 1) / 2;  // 2 rows per gather block

  // ----- CSR build (edges shared by both layers) -----
  hipMemsetAsync(cnt, 0, (size_t)(n + 1) * 4, stream);
  deg_count<<<EB, 256, 0, stream>>>(ed, cnt, nE);
  scan1<<<NB, 256, 0, stream>>>(cnt, excl, bsum, n);
  scan2<<<1, 256, 0, stream>>>(bsum, boff, NB);
  scan3<<<NB, 256, 0, stream>>>(excl, boff, rowstart, fill, n, nE);
  bucket_fill<<<EB, 256, 0, stream>>>(es, ed, ew, fill, sedge, nE);

  // ----- layer 1 -----
  cvt_rows_bf16<<<n, 256, 0, stream>>>(x, u16);
  cvt_w_bf16<<<1024, 256, 0, stream>>>(W1, w16, 1023, 1024);
  gemm_bt256<<<NWG2, 512, 0, stream>>>(u16, w16, b1, raw16);
  row_scale<<<n, 256, 0, stream>>>(raw16, sc_tab, sK1);
  gather_centroid_tangent<<<GB, 256, 0, stream>>>(raw16, sc_tab, rowstart, sedge, u16, sK1, n);

  // ----- layer 2 -----
  cvt_w_bf16<<<1024, 256, 0, stream>>>(W2, w16, 1023, 1023);
  gemm_bt256<<<NWG2, 512, 0, stream>>>(u16, w16, b2, raw16);
  row_scale<<<n, 256, 0, stream>>>(raw16, sc_tab, sK2);
  gather_centroid_final<<<GB, 256, 0, stream>>>(raw16, sc_tab, rowstart, sedge, y, sK2, sK3, n);
}

// Round 6
// 715.556 us; speedup vs baseline: 1.1400x; 1.1400x over previous
//
#include <hip/hip_runtime.h>
#include <math.h>

#define EPSF 1e-7f
#define KPAD 1024
#define M_PAD 50176   // 196 * 256
#define NWG2 784      // 196 * 4 = 8 * 98

typedef __attribute__((ext_vector_type(8))) short bf16x8;
typedef __attribute__((ext_vector_type(4))) float f32x4;
typedef __attribute__((ext_vector_type(4))) unsigned short us4;
typedef __attribute__((ext_vector_type(8))) unsigned short us8;

__device__ inline unsigned short f2bf(float f) {
  unsigned u = __float_as_uint(f);
  return (unsigned short)((u + 0x7FFFu + ((u >> 16) & 1u)) >> 16);
}
__device__ inline float bf2f(unsigned short s) {
  return __uint_as_float(((unsigned)s) << 16);
}

__device__ inline float block_sum256(float v, float* s4) {
#pragma unroll
  for (int o = 32; o > 0; o >>= 1) v += __shfl_down(v, o);
  int lane = threadIdx.x & 63, w = threadIdx.x >> 6;
  __syncthreads();
  if (lane == 0) s4[w] = v;
  __syncthreads();
  return s4[0] + s4[1] + s4[2] + s4[3];
}

__device__ inline void gload_lds16(const void* g, void* l) {
  __builtin_amdgcn_global_load_lds((const __attribute__((address_space(1))) void*)g,
                                   (__attribute__((address_space(3))) void*)l, 16, 0, 0);
}

// ---------- conversions ----------
__global__ __launch_bounds__(256) void cvt_rows_bf16(const float* __restrict__ x,
                                                     unsigned short* __restrict__ o) {
  int i = blockIdx.x, t = threadIdx.x;
  float4 v = *(const float4*)(x + (size_t)i * 1024 + 4 * t);
  us4 u = {f2bf(v.x), f2bf(v.y), f2bf(v.z), f2bf(v.w)};
  *(us4*)(o + (size_t)i * 1024 + 4 * t) = u;
}

__global__ __launch_bounds__(256) void cvt_w_bf16(const float* __restrict__ W,
                                                  unsigned short* __restrict__ o,
                                                  int rows, int cols) {
  int r = blockIdx.x, t = threadIdx.x;
  int c0 = 4 * t;
  us4 u;
#pragma unroll
  for (int j = 0; j < 4; ++j) {
    int c = c0 + j;
    float v = (r < rows && c < cols) ? W[(size_t)r * cols + c] : 0.0f;
    u[j] = f2bf(v);
  }
  *(us4*)(o + (size_t)r * 1024 + c0) = u;
}

// ---------- GEMM 256x256, BK=64, 8-phase double-buffer, counted vmcnt(6) ----------
// C[i][j] = bf16(sum_k A16[i][k] * B16[j][k] + bias[j])
// LDS: lA/lB [buf p][half h][128 rows][8 slots of 8 bf16]; slot sigma at row r holds
// global granule sigma^(r&7)  (XOR swizzle, inverse-swizzled global source, G21).
__global__ __launch_bounds__(512, 2) void gemm_bt256(const unsigned short* __restrict__ A,
                                                     const unsigned short* __restrict__ B,
                                                     const float* __restrict__ bias,
                                                     unsigned short* __restrict__ C) {
  __shared__ unsigned short lA[2 * 2 * 8192];  // 64 KB
  __shared__ unsigned short lB[2 * 2 * 8192];  // 64 KB
  const int wg = blockIdx.x;
  const int swz = (wg & 7) * 98 + (wg >> 3);  // bijective: 784 = 8*98
  const int bm = swz >> 2, bn = swz & 3;
  const int tid = threadIdx.x;
  const int wave = tid >> 6, lane = tid & 63;
  const int wr = wave >> 2, wc = wave & 3;  // 2 x 4 wave grid, 128x64 per wave
  const int fr = lane & 15, fg = lane >> 4;

  const unsigned short* Abase = A + (size_t)bm * 256 * KPAD;
  const unsigned short* Bbase = B + (size_t)bn * 256 * KPAD;

  // fragment-read constants (shorts offsets)
  const int aHalf = wr * 8192;
  const int bHalf = (wc >> 1) * 8192;
  const int lrB0 = (wc & 1) * 64;
  int ps[2];
#pragma unroll
  for (int s = 0; s < 2; ++s) ps[s] = (((s << 2) + fg) ^ (fr & 7)) << 3;

  // staging constants
  const int sRow8 = lane >> 3;   // row within 8-row group, = row&7
  const int sDst = wave * 512 + lane * 8;          // + q*4096 (+half*8192 +p*16384)
  const int sGran = ((lane & 7) ^ sRow8) << 3;     // global k-granule offset (shorts)

  f32x4 acc[8][4];
#pragma unroll
  for (int m = 0; m < 8; ++m)
#pragma unroll
    for (int n2 = 0; n2 < 4; ++n2) acc[m][n2] = (f32x4)0.0f;

  bf16x8 af[4][2], bf[4][2];

  auto STAGE_A = [&](int t, int h) {
    const int p = t & 1;
#pragma unroll
    for (int q = 0; q < 2; ++q) {
      int row = h * 128 + q * 64 + wave * 8 + sRow8;
      gload_lds16(Abase + (size_t)row * KPAD + t * 64 + sGran,
                  &lA[p * 16384 + h * 8192 + q * 4096 + sDst]);
    }
  };
  auto STAGE_B = [&](int t, int h) {
    const int p = t & 1;
#pragma unroll
    for (int q = 0; q < 2; ++q) {
      int row = h * 128 + q * 64 + wave * 8 + sRow8;
      gload_lds16(Bbase + (size_t)row * KPAD + t * 64 + sGran,
                  &lB[p * 16384 + h * 8192 + q * 4096 + sDst]);
    }
  };
  auto LDA4 = [&](int p, int mg) {  // a[mg*4 .. mg*4+3], both k-slices (8 ds_read_b128)
#pragma unroll
    for (int mi = 0; mi < 4; ++mi) {
      int ro = p * 16384 + aHalf + ((mg * 4 + mi) * 16 + fr) * 64;
#pragma unroll
      for (int s = 0; s < 2; ++s) af[mi][s] = *(const bf16x8*)&lA[ro + ps[s]];
    }
  };
  auto LDB2 = [&](int p, int ng) {  // b[ng*2 .. ng*2+1], both k-slices (4 ds_read_b128)
#pragma unroll
    for (int ni = 0; ni < 2; ++ni) {
      int ro = p * 16384 + bHalf + (lrB0 + (ng * 2 + ni) * 16 + fr) * 64;
#pragma unroll
      for (int s = 0; s < 2; ++s) bf[ng * 2 + ni][s] = *(const bf16x8*)&lB[ro + ps[s]];
    }
  };
  auto MM = [&](int mq, int nq) {  // 16 MFMA: one C-quadrant
    __builtin_amdgcn_s_setprio(1);
#pragma unroll
    for (int mi = 0; mi < 4; ++mi)
#pragma unroll
      for (int ni = 0; ni < 2; ++ni)
#pragma unroll
        for (int s = 0; s < 2; ++s)
          acc[mq * 4 + mi][nq * 2 + ni] = __builtin_amdgcn_mfma_f32_16x16x32_bf16(
              af[mi][s], bf[nq * 2 + ni][s], acc[mq * 4 + mi][nq * 2 + ni], 0, 0, 0);
    __builtin_amdgcn_s_setprio(0);
  };
#define BAR() __builtin_amdgcn_s_barrier()

  // ----- prologue: tile0 (8 loads) + tile1 B0,B1,A0 (6 loads); wait oldest 8 -----
  STAGE_B(0, 0); STAGE_B(0, 1); STAGE_A(0, 0); STAGE_A(0, 1);
  STAGE_B(1, 0); STAGE_B(1, 1); STAGE_A(1, 0);
  asm volatile("s_waitcnt vmcnt(6)" ::: "memory");
  BAR();

  // ----- main loop: 7 iterations, tiles 0..13; stages tiles 2..15 -----
#pragma unroll 1
  for (int it = 0; it < 7; ++it) {
    const int t0 = 2 * it, t1 = t0 + 1;
    // P1: read buf0 a[0-3],b[0-1]; stage A1(t1)->buf1
    LDA4(0, 0); LDB2(0, 0);
    STAGE_A(t1, 1);
    BAR(); MM(0, 0); BAR();
    // P2: read buf0 b[2-3]
    LDB2(0, 1);
    BAR(); MM(0, 1); BAR();
    // P3: read buf0 a[4-7]; stage B0(t0+2)->buf0 (buf0-B free after P2)
    LDA4(0, 1);
    STAGE_B(t0 + 2, 0);
    BAR(); MM(1, 0); BAR();
    // P4: stage B1(t0+2), A0(t0+2) (buf0-A free after P3); vmcnt(6) => buf1 ready
    STAGE_B(t0 + 2, 1); STAGE_A(t0 + 2, 0);
    asm volatile("s_waitcnt vmcnt(6)" ::: "memory");
    BAR(); MM(1, 1); BAR();
    // P5: read buf1 a[0-3],b[0-1]; stage A1(t0+2)->buf0
    LDA4(1, 0); LDB2(1, 0);
    STAGE_A(t0 + 2, 1);
    BAR(); MM(0, 0); BAR();
    // P6: read buf1 b[2-3]
    LDB2(1, 1);
    BAR(); MM(0, 1); BAR();
    // P7: read buf1 a[4-7]; stage B0(t1+2)->buf1 (buf1-B free after P6)
    LDA4(1, 1);
    STAGE_B(t1 + 2, 0);
    BAR(); MM(1, 0); BAR();
    // P8: stage B1(t1+2), A0(t1+2) (buf1-A free after P7); vmcnt(6) => buf0 ready
    STAGE_B(t1 + 2, 1); STAGE_A(t1 + 2, 0);
    asm volatile("s_waitcnt vmcnt(6)" ::: "memory");
    BAR(); MM(1, 1); BAR();
  }

  // ----- tail: tiles 14 (buf0), 15 (buf1); no stages, no LDS writes -----
  asm volatile("s_waitcnt vmcnt(0)" ::: "memory");
  BAR();
#pragma unroll
  for (int p = 0; p < 2; ++p) {
    LDA4(p, 0); LDB2(p, 0); MM(0, 0);
    LDB2(p, 1); MM(0, 1);
    LDA4(p, 1); MM(1, 0); MM(1, 1);
  }
#undef BAR

  // ----- epilogue -----
  const int crow0 = bm * 256 + wr * 128;
  const int ccol0 = bn * 256 + wc * 64;
#pragma unroll
  for (int m = 0; m < 8; ++m) {
#pragma unroll
    for (int n2 = 0; n2 < 4; ++n2) {
      int col = ccol0 + n2 * 16 + fr;
      float bv = (col < 1023) ? bias[col] : 0.0f;
      int row0 = crow0 + m * 16 + fg * 4;
      unsigned short* cp = C + (size_t)row0 * 1024 + col;
#pragma unroll
      for (int j = 0; j < 4; ++j) cp[(size_t)j * 1024] = f2bf(acc[m][n2][j] + bv);
    }
  }
}

// ---------- per-row expmap scale: sc table + patch raw[1023] = h0/sc ----------
__global__ __launch_bounds__(256) void row_scale(unsigned short* __restrict__ raw,
                                                 float* __restrict__ sc_tab, float sqrtK) {
  __shared__ float s4[4];
  int i = blockIdx.x, t = threadIdx.x;
  const us4 v = *(const us4*)(raw + (size_t)i * 1024 + 4 * t);
  float f0 = bf2f(v[0]), f1 = bf2f(v[1]), f2 = bf2f(v[2]), f3 = bf2f(v[3]);
  if (t == 255) f3 = 0.0f;  // col 1023 is pad
  float ss = block_sum256(f0 * f0 + f1 * f1 + f2 * f2 + f3 * f3, s4);
  float un = fmaxf(sqrtf(ss), EPSF);
  float tt = un / sqrtK;
  float e = expf(tt);
  float ch = 0.5f * (e + 1.0f / e), sh = 0.5f * (e - 1.0f / e);
  float h0 = sqrtK * ch, sc = sqrtK * sh / un;
  if (t == 0) sc_tab[i] = sc;
  if (t == 255) raw[(size_t)i * 1024 + 1023] = f2bf(h0 / sc);
}

// ---------- CSR build ----------
__global__ __launch_bounds__(256) void deg_count(const int* __restrict__ ed, int* __restrict__ cnt,
                                                 int nE) {
  int i = blockIdx.x * 256 + threadIdx.x;
  if (i < nE) atomicAdd(&cnt[ed[i]], 1);
}

__global__ __launch_bounds__(256) void scan1(const int* __restrict__ cnt, int* __restrict__ excl,
                                             int* __restrict__ bsum, int n) {
  __shared__ int s[256];
  int t = threadIdx.x;
  int i = blockIdx.x * 256 + t;
  int v = (i < n) ? cnt[i] : 0;
  s[t] = v;
  __syncthreads();
#pragma unroll
  for (int o = 1; o < 256; o <<= 1) {
    int add = (t >= o) ? s[t - o] : 0;
    __syncthreads();
    s[t] += add;
    __syncthreads();
  }
  if (i < n) excl[i] = s[t] - v;
  if (t == 255) bsum[blockIdx.x] = s[t];
}

__global__ __launch_bounds__(256) void scan2(int* __restrict__ bsum, int* __restrict__ boff,
                                             int nb) {
  __shared__ int s[256];
  int t = threadIdx.x;
  int v = (t < nb) ? bsum[t] : 0;
  s[t] = v;
  __syncthreads();
#pragma unroll
  for (int o = 1; o < 256; o <<= 1) {
    int add = (t >= o) ? s[t - o] : 0;
    __syncthreads();
    s[t] += add;
    __syncthreads();
  }
  if (t < nb) boff[t] = s[t] - v;
}

__global__ __launch_bounds__(256) void scan3(int* __restrict__ excl, const int* __restrict__ boff,
                                             int* __restrict__ rowstart, int* __restrict__ fill,
                                             int n, int nE) {
  int i = blockIdx.x * 256 + threadIdx.x;
  if (i < n) {
    int v = excl[i] + boff[blockIdx.x];
    rowstart[i] = v;
    fill[i] = v;
  }
  if (i == 0) rowstart[n] = nE;
}

__global__ __launch_bounds__(256) void bucket_fill(const int* __restrict__ es,
                                                   const int* __restrict__ ed,
                                                   const float* __restrict__ ew,
                                                   int* __restrict__ fill,
                                                   int2* __restrict__ sedge, int nE) {
  int i = blockIdx.x * 256 + threadIdx.x;
  if (i < nE) {
    int d = ed[i];
    int pos = atomicAdd(&fill[d], 1);
    sedge[pos] = make_int2(es[i], __float_as_int(ew[i]));
  }
}

// ---------- gather core: acc[8] += (ew*sc[src]) * h[src][8t..8t+7], 4-deep MLP ----------
__device__ inline void gather_row(const unsigned short* __restrict__ h,
                                  const float* __restrict__ sc,
                                  const int2* __restrict__ sedge, int j0, int j1, int t,
                                  float* acc) {
  int j = j0;
  for (; j + 4 <= j1; j += 4) {
    int2 e0 = sedge[j], e1 = sedge[j + 1], e2 = sedge[j + 2], e3 = sedge[j + 3];
    float w0 = __int_as_float(e0.y) * sc[e0.x];
    float w1 = __int_as_float(e1.y) * sc[e1.x];
    float w2 = __int_as_float(e2.y) * sc[e2.x];
    float w3 = __int_as_float(e3.y) * sc[e3.x];
    us8 v0 = *(const us8*)(h + (size_t)e0.x * 1024 + 8 * t);
    us8 v1 = *(const us8*)(h + (size_t)e1.x * 1024 + 8 * t);
    us8 v2 = *(const us8*)(h + (size_t)e2.x * 1024 + 8 * t);
    us8 v3 = *(const us8*)(h + (size_t)e3.x * 1024 + 8 * t);
#pragma unroll
    for (int q = 0; q < 8; ++q) {
      acc[q] += w0 * bf2f(v0[q]);
      acc[q] += w1 * bf2f(v1[q]);
      acc[q] += w2 * bf2f(v2[q]);
      acc[q] += w3 * bf2f(v3[q]);
    }
  }
  for (; j < j1; ++j) {
    int2 e = sedge[j];
    float w = __int_as_float(e.y) * sc[e.x];
    us8 v = *(const us8*)(h + (size_t)e.x * 1024 + 8 * t);
#pragma unroll
    for (int q = 0; q < 8; ++q) acc[q] += w * bf2f(v[q]);
  }
}

// ---------- gather + centroid + logmap0 + relu -> bf16 tangent (layer-1 tail) ----------
__global__ __launch_bounds__(256) void gather_centroid_tangent(
    const unsigned short* __restrict__ h, const float* __restrict__ sc,
    const int* __restrict__ rs, const int2* __restrict__ sedge,
    unsigned short* __restrict__ u16, float sqrtK, int n) {
  __shared__ float s4[4];
  __shared__ float sm0[2];
  int g = threadIdx.x >> 7;   // sub-block 0/1
  int t = threadIdx.x & 127;  // 0..127
  int i = blockIdx.x * 2 + g;
  bool alive = (i < n);
  int j0 = alive ? rs[i] : 0, j1 = alive ? rs[i + 1] : 0;
  float acc[8] = {0.f, 0.f, 0.f, 0.f, 0.f, 0.f, 0.f, 0.f};
  gather_row(h, sc, sedge, j0, j1, t, acc);
  if (t == 127) sm0[g] = acc[7];  // time coord (col 1023)
  __syncthreads();
  float m0 = sm0[g];
  if (t == 127) acc[7] = 0.0f;
  float ssl = 0.f;
#pragma unroll
  for (int q = 0; q < 8; ++q) ssl += acc[q] * acc[q];
#pragma unroll
  for (int o = 32; o > 0; o >>= 1) ssl += __shfl_down(ssl, o);
  int lane = threadIdx.x & 63, wv = threadIdx.x >> 6;
  if (lane == 0) s4[wv] = ssl;
  __syncthreads();
  float ss = s4[2 * g] + s4[2 * g + 1];

  float l = ss - m0 * m0;
  float denom = sqrtf(fmaxf(fabsf(l), EPSF));
  float c = sqrtK / denom;
  float xn = fmaxf(c * sqrtf(ss), EPSF);
  float theta = fmaxf(m0 / denom, 1.0f + EPSF);
  float d = sqrtK * acoshf(theta);
  float f = c * (d / xn);
  us8 u;
#pragma unroll
  for (int q = 0; q < 8; ++q) u[q] = f2bf(fmaxf(acc[q], 0.0f) * f);
  if (t == 127) u[7] = 0;  // col 1023 pad
  if (alive) *(us8*)(u16 + (size_t)i * 1024 + 8 * t) = u;
}

// ---------- gather + centroid + logmap + relu + expmap + proj -> y (layer-2 tail) ----------
__global__ __launch_bounds__(256) void gather_centroid_final(
    const unsigned short* __restrict__ h, const float* __restrict__ sc,
    const int* __restrict__ rs, const int2* __restrict__ sedge, float* __restrict__ y,
    float sqrtKin, float sqrtKout, int n) {
  __shared__ float s4[4];
  __shared__ float s4b[4];
  __shared__ float sm0[2];
  int g = threadIdx.x >> 7;
  int t = threadIdx.x & 127;
  int i = blockIdx.x * 2 + g;
  bool alive = (i < n);
  int j0 = alive ? rs[i] : 0, j1 = alive ? rs[i + 1] : 0;
  float acc[8] = {0.f, 0.f, 0.f, 0.f, 0.f, 0.f, 0.f, 0.f};
  gather_row(h, sc, sedge, j0, j1, t, acc);
  if (t == 127) sm0[g] = acc[7];
  __syncthreads();
  float m0 = sm0[g];
  if (t == 127) acc[7] = 0.0f;
  float ssl = 0.f;
#pragma unroll
  for (int q = 0; q < 8; ++q) ssl += acc[q] * acc[q];
#pragma unroll
  for (int o = 32; o > 0; o >>= 1) ssl += __shfl_down(ssl, o);
  int lane = threadIdx.x & 63, wv = threadIdx.x >> 6;
  if (lane == 0) s4[wv] = ssl;
  __syncthreads();
  float ss = s4[2 * g] + s4[2 * g + 1];

  float l = ss - m0 * m0;
  float denom = sqrtf(fmaxf(fabsf(l), EPSF));
  float c = sqrtKin / denom;
  float xn = fmaxf(c * sqrtf(ss), EPSF);
  float theta = fmaxf(m0 / denom, 1.0f + EPSF);
  float d = sqrtKin * acoshf(theta);
  float f = c * (d / xn);
  float o_[8];
#pragma unroll
  for (int q = 0; q < 8; ++q) o_[q] = fmaxf(acc[q], 0.0f) * f;
  if (t == 127) o_[7] = 0.0f;
  float ss2l = 0.f;
#pragma unroll
  for (int q = 0; q < 8; ++q) ss2l += o_[q] * o_[q];
#pragma unroll
  for (int o = 32; o > 0; o >>= 1) ss2l += __shfl_down(ss2l, o);
  if (lane == 0) s4b[wv] = ss2l;
  __syncthreads();
  float ss2 = s4b[2 * g] + s4b[2 * g + 1];

  float un = fmaxf(sqrtf(ss2), EPSF);
  float tt = un / sqrtKout;
  float e = expf(tt);
  float ch = 0.5f * (e + 1.0f / e), sh = 0.5f * (e - 1.0f / e);
  float y0 = sqrtKout * ch, scale = sqrtKout * sh / un;
  if (alive) {
    float* yr = y + (size_t)i * 1024;
    int c0 = 8 * t;
#pragma unroll
    for (int q = 0; q < 8; ++q) {
      int col = c0 + q;
      if (col < 1023) yr[1 + col] = scale * o_[q];
    }
    if (t == 0) yr[0] = y0;
  }
}

extern "C" void kernel_launch(void* const* d_in, const int* in_sizes, int n_in,
                              void* d_out, int out_size, void* d_ws, size_t ws_size,
                              hipStream_t stream) {
  const float* x = (const float*)d_in[0];
  const int* es = (const int*)d_in[1];
  const int* ed = (const int*)d_in[2];
  const float* ew = (const float*)d_in[3];
  const float* W1 = (const float*)d_in[4];
  const float* b1 = (const float*)d_in[5];
  const float* W2 = (const float*)d_in[6];
  const float* b2 = (const float*)d_in[7];
  float* y = (float*)d_out;

  const int n = in_sizes[0] / 1024;  // 50000
  const int nE = in_sizes[1];        // 400000
  const int NB = (n + 255) / 256;    // 196
  const int EB = (nE + 255) / 256;

  // workspace layout (offsets 256B-aligned)
  char* ws = (char*)d_ws;
  size_t off = 0;
  auto alloc = [&](size_t bytes) {
    void* p = ws + off;
    off += (bytes + 255) & ~(size_t)255;
    return p;
  };
  unsigned short* u16 = (unsigned short*)alloc((size_t)M_PAD * 1024 * 2);
  unsigned short* w16 = (unsigned short*)alloc((size_t)1024 * 1024 * 2);
  unsigned short* raw16 = (unsigned short*)alloc((size_t)M_PAD * 1024 * 2);
  float* sc_tab = (float*)alloc((size_t)M_PAD * 4);
  int* cnt = (int*)alloc((size_t)(n + 1) * 4);
  int* excl = (int*)alloc((size_t)n * 4);
  int* rowstart = (int*)alloc((size_t)(n + 1) * 4);
  int* fill = (int*)alloc((size_t)n * 4);
  int* bsum = (int*)alloc(256 * 4);
  int* boff = (int*)alloc(256 * 4);
  int2* sedge = (int2*)alloc((size_t)nE * 8);

  const float sK1 = 1.0f;                 // sqrt(K_IN)
  const float sK2 = 1.0488088481701516f;  // sqrt(1.1)
  const float sK3 = 1.0954451150103321f;  // sqrt(1.2)

  const int GB = (n + 1) / 2;  // 2 rows per gather block

  // ----- CSR build (edges shared by both layers) -----
  hipMemsetAsync(cnt, 0, (size_t)(n + 1) * 4, stream);
  deg_count<<<EB, 256, 0, stream>>>(ed, cnt, nE);
  scan1<<<NB, 256, 0, stream>>>(cnt, excl, bsum, n);
  scan2<<<1, 256, 0, stream>>>(bsum, boff, NB);
  scan3<<<NB, 256, 0, stream>>>(excl, boff, rowstart, fill, n, nE);
  bucket_fill<<<EB, 256, 0, stream>>>(es, ed, ew, fill, sedge, nE);

  // ----- layer 1 -----
  cvt_rows_bf16<<<n, 256, 0, stream>>>(x, u16);
  cvt_w_bf16<<<1024, 256, 0, stream>>>(W1, w16, 1023, 1024);
  gemm_bt256<<<NWG2, 512, 0, stream>>>(u16, w16, b1, raw16);
  row_scale<<<n, 256, 0, stream>>>(raw16, sc_tab, sK1);
  gather_centroid_tangent<<<GB, 256, 0, stream>>>(raw16, sc_tab, rowstart, sedge, u16, sK1, n);

  // ----- layer 2 -----
  cvt_w_bf16<<<1024, 256, 0, stream>>>(W2, w16, 1023, 1023);
  gemm_bt256<<<NWG2, 512, 0, stream>>>(u16, w16, b2, raw16);
  row_scale<<<n, 256, 0, stream>>>(raw16, sc_tab, sK2);
  gather_centroid_final<<<GB, 256, 0, stream>>>(raw16, sc_tab, rowstart, sedge, y, sK2, sK3, n);
}

// Round 7
// 686.174 us; speedup vs baseline: 1.1888x; 1.0428x over previous
//
#include <hip/hip_runtime.h>
#include <math.h>

#define EPSF 1e-7f
#define KPAD 1024
#define M_PAD 50176   // 196 * 256
#define NWG2 784      // 196 * 4 = 8 * 98

typedef __attribute__((ext_vector_type(8))) short bf16x8;
typedef __attribute__((ext_vector_type(4))) float f32x4;
typedef __attribute__((ext_vector_type(4))) unsigned short us4;
typedef __attribute__((ext_vector_type(8))) unsigned short us8;

__device__ inline unsigned short f2bf(float f) {
  unsigned u = __float_as_uint(f);
  return (unsigned short)((u + 0x7FFFu + ((u >> 16) & 1u)) >> 16);
}
__device__ inline float bf2f(unsigned short s) {
  return __uint_as_float(((unsigned)s) << 16);
}

__device__ inline void gload_lds16(const void* g, void* l) {
  __builtin_amdgcn_global_load_lds((const __attribute__((address_space(1))) void*)g,
                                   (__attribute__((address_space(3))) void*)l, 16, 0, 0);
}

// ---------- conversions ----------
__global__ __launch_bounds__(256) void cvt_rows_bf16(const float* __restrict__ x,
                                                     unsigned short* __restrict__ o) {
  int i = blockIdx.x, t = threadIdx.x;
  float4 v = *(const float4*)(x + (size_t)i * 1024 + 4 * t);
  us4 u = {f2bf(v.x), f2bf(v.y), f2bf(v.z), f2bf(v.w)};
  *(us4*)(o + (size_t)i * 1024 + 4 * t) = u;
}

__global__ __launch_bounds__(256) void cvt_w_bf16(const float* __restrict__ W,
                                                  unsigned short* __restrict__ o,
                                                  int rows, int cols) {
  int r = blockIdx.x, t = threadIdx.x;
  int c0 = 4 * t;
  us4 u;
#pragma unroll
  for (int j = 0; j < 4; ++j) {
    int c = c0 + j;
    float v = (r < rows && c < cols) ? W[(size_t)r * cols + c] : 0.0f;
    u[j] = f2bf(v);
  }
  *(us4*)(o + (size_t)r * 1024 + c0) = u;
}

// ---------- GEMM 256x256, BK=64, 8-phase double-buffer, counted vmcnt(6) ----------
// C[i][j] = bf16(sum_k A16[i][k] * B16[j][k] + bias[j]); also emits per-row
// sum-of-squares partial rowss[row*4 + bn] for the expmap norm (fused row_scale).
__global__ __launch_bounds__(512, 2) void gemm_bt256(const unsigned short* __restrict__ A,
                                                     const unsigned short* __restrict__ B,
                                                     const float* __restrict__ bias,
                                                     unsigned short* __restrict__ C,
                                                     float* __restrict__ rowss) {
  __shared__ unsigned short lA[2 * 2 * 8192];  // 64 KB
  __shared__ unsigned short lB[2 * 2 * 8192];  // 64 KB
  const int wg = blockIdx.x;
  const int swz = (wg & 7) * 98 + (wg >> 3);  // bijective: 784 = 8*98
  const int bm = swz >> 2, bn = swz & 3;
  const int tid = threadIdx.x;
  const int wave = tid >> 6, lane = tid & 63;
  const int wr = wave >> 2, wc = wave & 3;  // 2 x 4 wave grid, 128x64 per wave
  const int fr = lane & 15, fg = lane >> 4;

  const unsigned short* Abase = A + (size_t)bm * 256 * KPAD;
  const unsigned short* Bbase = B + (size_t)bn * 256 * KPAD;

  // fragment-read constants (shorts offsets)
  const int aHalf = wr * 8192;
  const int bHalf = (wc >> 1) * 8192;
  const int lrB0 = (wc & 1) * 64;
  int ps[2];
#pragma unroll
  for (int s = 0; s < 2; ++s) ps[s] = (((s << 2) + fg) ^ (fr & 7)) << 3;

  // staging constants
  const int sRow8 = lane >> 3;   // row within 8-row group, = row&7
  const int sDst = wave * 512 + lane * 8;          // + q*4096 (+half*8192 +p*16384)
  const int sGran = ((lane & 7) ^ sRow8) << 3;     // global k-granule offset (shorts)

  f32x4 acc[8][4];
#pragma unroll
  for (int m = 0; m < 8; ++m)
#pragma unroll
    for (int n2 = 0; n2 < 4; ++n2) acc[m][n2] = (f32x4)0.0f;

  bf16x8 af[4][2], bf[4][2];

  auto STAGE_A = [&](int t, int h) {
    const int p = t & 1;
#pragma unroll
    for (int q = 0; q < 2; ++q) {
      int row = h * 128 + q * 64 + wave * 8 + sRow8;
      gload_lds16(Abase + (size_t)row * KPAD + t * 64 + sGran,
                  &lA[p * 16384 + h * 8192 + q * 4096 + sDst]);
    }
  };
  auto STAGE_B = [&](int t, int h) {
    const int p = t & 1;
#pragma unroll
    for (int q = 0; q < 2; ++q) {
      int row = h * 128 + q * 64 + wave * 8 + sRow8;
      gload_lds16(Bbase + (size_t)row * KPAD + t * 64 + sGran,
                  &lB[p * 16384 + h * 8192 + q * 4096 + sDst]);
    }
  };
  auto LDA4 = [&](int p, int mg) {  // a[mg*4 .. mg*4+3], both k-slices (8 ds_read_b128)
#pragma unroll
    for (int mi = 0; mi < 4; ++mi) {
      int ro = p * 16384 + aHalf + ((mg * 4 + mi) * 16 + fr) * 64;
#pragma unroll
      for (int s = 0; s < 2; ++s) af[mi][s] = *(const bf16x8*)&lA[ro + ps[s]];
    }
  };
  auto LDB2 = [&](int p, int ng) {  // b[ng*2 .. ng*2+1], both k-slices (4 ds_read_b128)
#pragma unroll
    for (int ni = 0; ni < 2; ++ni) {
      int ro = p * 16384 + bHalf + (lrB0 + (ng * 2 + ni) * 16 + fr) * 64;
#pragma unroll
      for (int s = 0; s < 2; ++s) bf[ng * 2 + ni][s] = *(const bf16x8*)&lB[ro + ps[s]];
    }
  };
  auto MM = [&](int mq, int nq) {  // 16 MFMA: one C-quadrant
    __builtin_amdgcn_s_setprio(1);
#pragma unroll
    for (int mi = 0; mi < 4; ++mi)
#pragma unroll
      for (int ni = 0; ni < 2; ++ni)
#pragma unroll
        for (int s = 0; s < 2; ++s)
          acc[mq * 4 + mi][nq * 2 + ni] = __builtin_amdgcn_mfma_f32_16x16x32_bf16(
              af[mi][s], bf[nq * 2 + ni][s], acc[mq * 4 + mi][nq * 2 + ni], 0, 0, 0);
    __builtin_amdgcn_s_setprio(0);
  };
#define BAR() __builtin_amdgcn_s_barrier()

  // ----- prologue: tile0 (8 loads) + tile1 B0,B1,A0 (6 loads); wait oldest 8 -----
  STAGE_B(0, 0); STAGE_B(0, 1); STAGE_A(0, 0); STAGE_A(0, 1);
  STAGE_B(1, 0); STAGE_B(1, 1); STAGE_A(1, 0);
  asm volatile("s_waitcnt vmcnt(6)" ::: "memory");
  BAR();

  // ----- main loop: 7 iterations, tiles 0..13; stages tiles 2..15 -----
#pragma unroll 1
  for (int it = 0; it < 7; ++it) {
    const int t0 = 2 * it, t1 = t0 + 1;
    // P1: read buf0 a[0-3],b[0-1]; stage A1(t1)->buf1
    LDA4(0, 0); LDB2(0, 0);
    STAGE_A(t1, 1);
    BAR(); MM(0, 0); BAR();
    // P2: read buf0 b[2-3]
    LDB2(0, 1);
    BAR(); MM(0, 1); BAR();
    // P3: read buf0 a[4-7]; stage B0(t0+2)->buf0 (buf0-B free after P2)
    LDA4(0, 1);
    STAGE_B(t0 + 2, 0);
    BAR(); MM(1, 0); BAR();
    // P4: stage B1(t0+2), A0(t0+2) (buf0-A free after P3); vmcnt(6) => buf1 ready
    STAGE_B(t0 + 2, 1); STAGE_A(t0 + 2, 0);
    asm volatile("s_waitcnt vmcnt(6)" ::: "memory");
    BAR(); MM(1, 1); BAR();
    // P5: read buf1 a[0-3],b[0-1]; stage A1(t0+2)->buf0
    LDA4(1, 0); LDB2(1, 0);
    STAGE_A(t0 + 2, 1);
    BAR(); MM(0, 0); BAR();
    // P6: read buf1 b[2-3]
    LDB2(1, 1);
    BAR(); MM(0, 1); BAR();
    // P7: read buf1 a[4-7]; stage B0(t1+2)->buf1 (buf1-B free after P6)
    LDA4(1, 1);
    STAGE_B(t1 + 2, 0);
    BAR(); MM(1, 0); BAR();
    // P8: stage B1(t1+2), A0(t1+2) (buf1-A free after P7); vmcnt(6) => buf0 ready
    STAGE_B(t1 + 2, 1); STAGE_A(t1 + 2, 0);
    asm volatile("s_waitcnt vmcnt(6)" ::: "memory");
    BAR(); MM(1, 1); BAR();
  }

  // ----- tail: tiles 14 (buf0), 15 (buf1); no stages, no LDS writes -----
  asm volatile("s_waitcnt vmcnt(0)" ::: "memory");
  BAR();
#pragma unroll
  for (int p = 0; p < 2; ++p) {
    LDA4(p, 0); LDB2(p, 0); MM(0, 0);
    LDB2(p, 1); MM(0, 1);
    LDA4(p, 1); MM(1, 0); MM(1, 1);
  }
#undef BAR

  // ----- epilogue: bf16 store + per-row sum-of-squares partial -----
  const int crow0 = bm * 256 + wr * 128;
  const int ccol0 = bn * 256 + wc * 64;
  float rs[8][4];
#pragma unroll
  for (int m = 0; m < 8; ++m)
#pragma unroll
    for (int j = 0; j < 4; ++j) rs[m][j] = 0.0f;
#pragma unroll
  for (int m = 0; m < 8; ++m) {
#pragma unroll
    for (int n2 = 0; n2 < 4; ++n2) {
      int col = ccol0 + n2 * 16 + fr;
      float bv = (col < 1023) ? bias[col] : 0.0f;
      int row0 = crow0 + m * 16 + fg * 4;
      unsigned short* cp = C + (size_t)row0 * 1024 + col;
#pragma unroll
      for (int j = 0; j < 4; ++j) {
        float v = acc[m][n2][j] + bv;
        cp[(size_t)j * 1024] = f2bf(v);
        rs[m][j] += v * v;
      }
    }
  }
  // reduce over the 16 fr-lanes of each fg group
#pragma unroll
  for (int m = 0; m < 8; ++m)
#pragma unroll
    for (int j = 0; j < 4; ++j) {
      float v = rs[m][j];
      v += __shfl_xor(v, 1);
      v += __shfl_xor(v, 2);
      v += __shfl_xor(v, 4);
      v += __shfl_xor(v, 8);
      rs[m][j] = v;
    }
  __syncthreads();  // pipeline fully drained (tail vmcnt(0)); reuse lA as scratch
  float* red = (float*)lA;  // [256 local rows][4 wc] floats = 4 KB
  if (fr == 0) {
#pragma unroll
    for (int m = 0; m < 8; ++m)
#pragma unroll
      for (int j = 0; j < 4; ++j)
        red[(wr * 128 + m * 16 + fg * 4 + j) * 4 + wc] = rs[m][j];
  }
  __syncthreads();
  if (tid < 256) {
    float s = red[tid * 4] + red[tid * 4 + 1] + red[tid * 4 + 2] + red[tid * 4 + 3];
    rowss[(size_t)(bm * 256 + tid) * 4 + bn] = s;
  }
}

// ---------- finalize per-row expmap scale from rowss partials ----------
__global__ __launch_bounds__(256) void row_finalize(const float* __restrict__ rowss,
                                                    unsigned short* __restrict__ raw,
                                                    float* __restrict__ sc_tab, float sqrtK,
                                                    int n) {
  int i = blockIdx.x * 256 + threadIdx.x;
  if (i >= n) return;
  float ss = rowss[4 * i] + rowss[4 * i + 1] + rowss[4 * i + 2] + rowss[4 * i + 3];
  float un = fmaxf(sqrtf(ss), EPSF);
  float tt = un / sqrtK;
  float e = expf(tt);
  float ch = 0.5f * (e + 1.0f / e), sh = 0.5f * (e - 1.0f / e);
  float h0 = sqrtK * ch, sc = sqrtK * sh / un;
  sc_tab[i] = sc;
  raw[(size_t)i * 1024 + 1023] = f2bf(h0 / sc);
}

// ---------- CSR build ----------
__global__ __launch_bounds__(256) void deg_count(const int* __restrict__ ed, int* __restrict__ cnt,
                                                 int nE) {
  int i = blockIdx.x * 256 + threadIdx.x;
  if (i < nE) atomicAdd(&cnt[ed[i]], 1);
}

__global__ __launch_bounds__(256) void scan1(const int* __restrict__ cnt, int* __restrict__ excl,
                                             int* __restrict__ bsum, int n) {
  __shared__ int s[256];
  int t = threadIdx.x;
  int i = blockIdx.x * 256 + t;
  int v = (i < n) ? cnt[i] : 0;
  s[t] = v;
  __syncthreads();
#pragma unroll
  for (int o = 1; o < 256; o <<= 1) {
    int add = (t >= o) ? s[t - o] : 0;
    __syncthreads();
    s[t] += add;
    __syncthreads();
  }
  if (i < n) excl[i] = s[t] - v;
  if (t == 255) bsum[blockIdx.x] = s[t];
}

__global__ __launch_bounds__(256) void scan2(int* __restrict__ bsum, int* __restrict__ boff,
                                             int nb) {
  __shared__ int s[256];
  int t = threadIdx.x;
  int v = (t < nb) ? bsum[t] : 0;
  s[t] = v;
  __syncthreads();
#pragma unroll
  for (int o = 1; o < 256; o <<= 1) {
    int add = (t >= o) ? s[t - o] : 0;
    __syncthreads();
    s[t] += add;
    __syncthreads();
  }
  if (t < nb) boff[t] = s[t] - v;
}

__global__ __launch_bounds__(256) void scan3(int* __restrict__ excl, const int* __restrict__ boff,
                                             int* __restrict__ rowstart, int* __restrict__ fill,
                                             int n, int nE) {
  int i = blockIdx.x * 256 + threadIdx.x;
  if (i < n) {
    int v = excl[i] + boff[blockIdx.x];
    rowstart[i] = v;
    fill[i] = v;
  }
  if (i == 0) rowstart[n] = nE;
}

__global__ __launch_bounds__(256) void bucket_fill(const int* __restrict__ es,
                                                   const int* __restrict__ ed,
                                                   const float* __restrict__ ew,
                                                   int* __restrict__ fill,
                                                   int2* __restrict__ sedge, int nE) {
  int i = blockIdx.x * 256 + threadIdx.x;
  if (i < nE) {
    int d = ed[i];
    int pos = atomicAdd(&fill[d], 1);
    sedge[pos] = make_int2(es[i], __float_as_int(ew[i]));
  }
}

// ---------- wave-per-row gather core: lane covers cols lane*8 (A) and 512+lane*8 (B)
__device__ inline void gather_row_wave(const unsigned short* __restrict__ h,
                                       const float* __restrict__ sc,
                                       const int2* __restrict__ sedge, int j0, int j1,
                                       int lane, float* fa, float* fb) {
  const char* hb = (const char*)h;
  int j = j0;
  for (; j + 2 <= j1; j += 2) {
    int2 e0 = sedge[j], e1 = sedge[j + 1];
    float w0 = __int_as_float(e0.y) * sc[e0.x];
    float w1 = __int_as_float(e1.y) * sc[e1.x];
    const us8* p0 = (const us8*)(hb + (((unsigned)e0.x) << 11)) + lane;
    const us8* p1 = (const us8*)(hb + (((unsigned)e1.x) << 11)) + lane;
    us8 a0 = p0[0], b0 = p0[64];
    us8 a1 = p1[0], b1 = p1[64];
#pragma unroll
    for (int q = 0; q < 8; ++q) {
      fa[q] += w0 * bf2f(a0[q]) + w1 * bf2f(a1[q]);
      fb[q] += w0 * bf2f(b0[q]) + w1 * bf2f(b1[q]);
    }
  }
  if (j < j1) {
    int2 e = sedge[j];
    float w = __int_as_float(e.y) * sc[e.x];
    const us8* p = (const us8*)(hb + (((unsigned)e.x) << 11)) + lane;
    us8 a = p[0], b = p[64];
#pragma unroll
    for (int q = 0; q < 8; ++q) {
      fa[q] += w * bf2f(a[q]);
      fb[q] += w * bf2f(b[q]);
    }
  }
}

__device__ inline float wave_sum(float v) {
#pragma unroll
  for (int m = 1; m <= 32; m <<= 1) v += __shfl_xor(v, m);
  return v;
}

// ---------- gather + centroid + logmap0 + relu -> bf16 tangent (layer-1 tail) ----------
__global__ __launch_bounds__(256) void gather_centroid_tangent(
    const unsigned short* __restrict__ h, const float* __restrict__ sc,
    const int* __restrict__ rs, const int2* __restrict__ sedge,
    unsigned short* __restrict__ u16, float sqrtK, int n) {
  int wv = threadIdx.x >> 6, lane = threadIdx.x & 63;
  int i = blockIdx.x * 4 + wv;
  if (i >= n) return;
  int j0 = rs[i], j1 = rs[i + 1];
  float fa[8] = {0.f, 0.f, 0.f, 0.f, 0.f, 0.f, 0.f, 0.f};
  float fb[8] = {0.f, 0.f, 0.f, 0.f, 0.f, 0.f, 0.f, 0.f};
  gather_row_wave(h, sc, sedge, j0, j1, lane, fa, fb);
  float m0 = __shfl(fb[7], 63);  // time coord (col 1023)
  if (lane == 63) fb[7] = 0.0f;
  float ssl = 0.f;
#pragma unroll
  for (int q = 0; q < 8; ++q) ssl += fa[q] * fa[q] + fb[q] * fb[q];
  float ss = wave_sum(ssl);

  float l = ss - m0 * m0;
  float denom = sqrtf(fmaxf(fabsf(l), EPSF));
  float c = sqrtK / denom;
  float xn = fmaxf(c * sqrtf(ss), EPSF);
  float theta = fmaxf(m0 / denom, 1.0f + EPSF);
  float d = sqrtK * acoshf(theta);
  float f = c * (d / xn);
  us8 ua, ub;
#pragma unroll
  for (int q = 0; q < 8; ++q) {
    ua[q] = f2bf(fmaxf(fa[q], 0.0f) * f);
    ub[q] = f2bf(fmaxf(fb[q], 0.0f) * f);
  }
  if (lane == 63) ub[7] = 0;  // col 1023 pad
  unsigned short* o = u16 + (size_t)i * 1024 + lane * 8;
  *(us8*)o = ua;
  *(us8*)(o + 512) = ub;
}

// ---------- gather + centroid + logmap + relu + expmap + proj -> y (layer-2 tail) ----------
__global__ __launch_bounds__(256) void gather_centroid_final(
    const unsigned short* __restrict__ h, const float* __restrict__ sc,
    const int* __restrict__ rs, const int2* __restrict__ sedge, float* __restrict__ y,
    float sqrtKin, float sqrtKout, int n) {
  int wv = threadIdx.x >> 6, lane = threadIdx.x & 63;
  int i = blockIdx.x * 4 + wv;
  if (i >= n) return;
  int j0 = rs[i], j1 = rs[i + 1];
  float fa[8] = {0.f, 0.f, 0.f, 0.f, 0.f, 0.f, 0.f, 0.f};
  float fb[8] = {0.f, 0.f, 0.f, 0.f, 0.f, 0.f, 0.f, 0.f};
  gather_row_wave(h, sc, sedge, j0, j1, lane, fa, fb);
  float m0 = __shfl(fb[7], 63);
  if (lane == 63) fb[7] = 0.0f;
  float ssl = 0.f;
#pragma unroll
  for (int q = 0; q < 8; ++q) ssl += fa[q] * fa[q] + fb[q] * fb[q];
  float ss = wave_sum(ssl);

  float l = ss - m0 * m0;
  float denom = sqrtf(fmaxf(fabsf(l), EPSF));
  float c = sqrtKin / denom;
  float xn = fmaxf(c * sqrtf(ss), EPSF);
  float theta = fmaxf(m0 / denom, 1.0f + EPSF);
  float d = sqrtKin * acoshf(theta);
  float f = c * (d / xn);
  float oa[8], ob[8];
  float ss2l = 0.f;
#pragma unroll
  for (int q = 0; q < 8; ++q) {
    oa[q] = fmaxf(fa[q], 0.0f) * f;
    ob[q] = fmaxf(fb[q], 0.0f) * f;
  }
  if (lane == 63) ob[7] = 0.0f;
#pragma unroll
  for (int q = 0; q < 8; ++q) ss2l += oa[q] * oa[q] + ob[q] * ob[q];
  float ss2 = wave_sum(ss2l);

  float un = fmaxf(sqrtf(ss2), EPSF);
  float tt = un / sqrtKout;
  float e = expf(tt);
  float ch = 0.5f * (e + 1.0f / e), sh = 0.5f * (e - 1.0f / e);
  float y0 = sqrtKout * ch, scale = sqrtKout * sh / un;
  float* yr = y + (size_t)i * 1024;
  int c0 = lane * 8;
#pragma unroll
  for (int q = 0; q < 8; ++q) {
    yr[1 + c0 + q] = scale * oa[q];
    int colb = 512 + c0 + q;
    if (colb < 1023) yr[1 + colb] = scale * ob[q];
  }
  if (lane == 0) yr[0] = y0;
}

extern "C" void kernel_launch(void* const* d_in, const int* in_sizes, int n_in,
                              void* d_out, int out_size, void* d_ws, size_t ws_size,
                              hipStream_t stream) {
  const float* x = (const float*)d_in[0];
  const int* es = (const int*)d_in[1];
  const int* ed = (const int*)d_in[2];
  const float* ew = (const float*)d_in[3];
  const float* W1 = (const float*)d_in[4];
  const float* b1 = (const float*)d_in[5];
  const float* W2 = (const float*)d_in[6];
  const float* b2 = (const float*)d_in[7];
  float* y = (float*)d_out;

  const int n = in_sizes[0] / 1024;  // 50000
  const int nE = in_sizes[1];        // 400000
  const int NB = (n + 255) / 256;    // 196
  const int EB = (nE + 255) / 256;

  // workspace layout (offsets 256B-aligned)
  char* ws = (char*)d_ws;
  size_t off = 0;
  auto alloc = [&](size_t bytes) {
    void* p = ws + off;
    off += (bytes + 255) & ~(size_t)255;
    return p;
  };
  unsigned short* u16 = (unsigned short*)alloc((size_t)M_PAD * 1024 * 2);
  unsigned short* w16 = (unsigned short*)alloc((size_t)1024 * 1024 * 2);
  unsigned short* raw16 = (unsigned short*)alloc((size_t)M_PAD * 1024 * 2);
  float* sc_tab = (float*)alloc((size_t)M_PAD * 4);
  float* rowss = (float*)alloc((size_t)M_PAD * 4 * 4);
  int* cnt = (int*)alloc((size_t)(n + 1) * 4);
  int* excl = (int*)alloc((size_t)n * 4);
  int* rowstart = (int*)alloc((size_t)(n + 1) * 4);
  int* fill = (int*)alloc((size_t)n * 4);
  int* bsum = (int*)alloc(256 * 4);
  int* boff = (int*)alloc(256 * 4);
  int2* sedge = (int2*)alloc((size_t)nE * 8);

  const float sK1 = 1.0f;                 // sqrt(K_IN)
  const float sK2 = 1.0488088481701516f;  // sqrt(1.1)
  const float sK3 = 1.0954451150103321f;  // sqrt(1.2)

  const int GB = (n + 3) / 4;  // 4 rows (waves) per gather block

  // ----- CSR build (edges shared by both layers) -----
  hipMemsetAsync(cnt, 0, (size_t)(n + 1) * 4, stream);
  deg_count<<<EB, 256, 0, stream>>>(ed, cnt, nE);
  scan1<<<NB, 256, 0, stream>>>(cnt, excl, bsum, n);
  scan2<<<1, 256, 0, stream>>>(bsum, boff, NB);
  scan3<<<NB, 256, 0, stream>>>(excl, boff, rowstart, fill, n, nE);
  bucket_fill<<<EB, 256, 0, stream>>>(es, ed, ew, fill, sedge, nE);

  // ----- layer 1 -----
  cvt_rows_bf16<<<n, 256, 0, stream>>>(x, u16);
  cvt_w_bf16<<<1024, 256, 0, stream>>>(W1, w16, 1023, 1024);
  gemm_bt256<<<NWG2, 512, 0, stream>>>(u16, w16, b1, raw16, rowss);
  row_finalize<<<NB, 256, 0, stream>>>(rowss, raw16, sc_tab, sK1, n);
  gather_centroid_tangent<<<GB, 256, 0, stream>>>(raw16, sc_tab, rowstart, sedge, u16, sK1, n);

  // ----- layer 2 -----
  cvt_w_bf16<<<1024, 256, 0, stream>>>(W2, w16, 1023, 1023);
  gemm_bt256<<<NWG2, 512, 0, stream>>>(u16, w16, b2, raw16, rowss);
  row_finalize<<<NB, 256, 0, stream>>>(rowss, raw16, sc_tab, sK2, n);
  gather_centroid_final<<<GB, 256, 0, stream>>>(raw16, sc_tab, rowstart, sedge, y, sK2, sK3, n);
}